// Round 11
// baseline (562.284 us; speedup 1.0000x reference)
//
#include <hip/hip_runtime.h>
#include <hip/hip_bf16.h>

// SharedMoEBlock: B=4,S=2048,D=1024,H=2048,E=8,topk=2
// Round 11: gateup reverted to unswizzled 2-way split (r10 XCD swizzle broke
// its natural L3 temporal locality: FETCH 255->660MB, 217->244us). k_down
// keeps XCD swizzle (helped) and widens to BN=256 w/ 512 threads, 8 waves
// 2Mx4N, per-wave 64x64 (same acc[4][4] inner structure) -> A re-reads 8->4.

#define T_TOK 8192
#define DDIM  1024
#define HDIM  2048
#define NEXP  8
#define BM    128
#define BK    64
#define MT_MAX 208
#define RMAX  25600   // max padded rows: routed <=17408 + shared 8192
#define CPAD  16      // cnt stride in ints (64B line per expert)

typedef __attribute__((ext_vector_type(4))) float f32x4;
typedef __attribute__((ext_vector_type(8))) short bfrag;
typedef __attribute__((ext_vector_type(4))) unsigned short u16x4;

static __device__ __forceinline__ unsigned short f2bf(float f) {
  __hip_bfloat16 h = __float2bfloat16(f);
  return __builtin_bit_cast(unsigned short, h);
}
static __device__ __forceinline__ float bf2f(unsigned short u) {
  __hip_bfloat16 h = __builtin_bit_cast(__hip_bfloat16, u);
  return __bfloat162float(h);
}
static __device__ __forceinline__ bfrag cvt8(const float* __restrict__ s) {
  f32x4 v0 = *(const f32x4*)s;
  f32x4 v1 = *(const f32x4*)(s + 4);
  bfrag h;
#pragma unroll
  for (int j = 0; j < 4; ++j) {
    h[j] = (short)f2bf(v0[j]);
    h[4 + j] = (short)f2bf(v1[j]);
  }
  return h;
}
static __device__ __forceinline__ bfrag pack8(f32x4 a, f32x4 b) {
  bfrag h;
#pragma unroll
  for (int j = 0; j < 4; ++j) {
    h[j] = (short)f2bf(a[j]);
    h[4 + j] = (short)f2bf(b[j]);
  }
  return h;
}
static __device__ __forceinline__ void gload16(const void* g, void* l) {
  __builtin_amdgcn_global_load_lds(
      (const __attribute__((address_space(1))) unsigned int*)g,
      (__attribute__((address_space(3))) unsigned int*)l, 16, 0, 0);
}

// ---------------- fp32 -> bf16 convert, 2 sets x 2 sources each ----------------
__global__ __launch_bounds__(256) void k_cvt4(
    const float* __restrict__ ea, const float* __restrict__ sa,
    unsigned short* __restrict__ da,
    const float* __restrict__ eb, const float* __restrict__ sb,
    unsigned short* __restrict__ db, long ne8, long ns8) {
  long tot = ne8 + ns8;
  long i = (long)blockIdx.x * blockDim.x + threadIdx.x;
  long stride = (long)gridDim.x * blockDim.x;
  for (; i < 2 * tot; i += stride) {
    long j = (i < tot) ? i : i - tot;
    const float* e = (i < tot) ? ea : eb;
    const float* sh = (i < tot) ? sa : sb;
    unsigned short* d = (i < tot) ? da : db;
    const float* s = (j < ne8) ? e + j * 8 : sh + (j - ne8) * 8;
    ((bfrag*)d)[j] = cvt8(s);
  }
}

// ---------------- fp32 -> bf16 convert, two sources ----------------
__global__ __launch_bounds__(256) void k_cvt2(const float* __restrict__ a, long na8,
                                              const float* __restrict__ b, long nb8,
                                              unsigned short* __restrict__ dst) {
  long i = (long)blockIdx.x * blockDim.x + threadIdx.x;
  long stride = (long)gridDim.x * blockDim.x;
  long n = na8 + nb8;
  for (; i < n; i += stride) {
    const float* s = (i < na8) ? a + i * 8 : b + (i - na8) * 8;
    ((bfrag*)dst)[i] = cvt8(s);
  }
}

// ---------------- router (+ fused x->bf16 conversion) ----------------
__global__ __launch_bounds__(256) void k_router(const float* __restrict__ x,
                                                const float* __restrict__ wr,
                                                unsigned short* __restrict__ xbf,
                                                int* __restrict__ cnt,
                                                int* __restrict__ lists,
                                                int* __restrict__ tokexp,
                                                int* __restrict__ tokrow,
                                                float* __restrict__ tokwt) {
  int wid = threadIdx.x >> 6, lane = threadIdx.x & 63;
  int t = blockIdx.x * 4 + wid;
  const float* xr = x + (long)t * DDIM;
  f32x4 xf[4];
#pragma unroll
  for (int j = 0; j < 4; ++j) xf[j] = ((const f32x4*)xr)[lane * 4 + j];
  // fused bf16 conversion of x
  bfrag* xrow = (bfrag*)(xbf + (long)t * DDIM);
  xrow[lane * 2] = pack8(xf[0], xf[1]);
  xrow[lane * 2 + 1] = pack8(xf[2], xf[3]);
  float L[NEXP];
#pragma unroll
  for (int e = 0; e < NEXP; ++e) {
    const f32x4* wrow = (const f32x4*)(wr + (long)e * DDIM);
    float p = 0.f;
#pragma unroll
    for (int j = 0; j < 4; ++j) {
      f32x4 w = wrow[lane * 4 + j];
      p += xf[j].x * w.x + xf[j].y * w.y + xf[j].z * w.z + xf[j].w * w.w;
    }
    for (int s = 1; s < 64; s <<= 1) p += __shfl_xor(p, s);
    L[e] = p;
  }
  int e1 = 0;
#pragma unroll
  for (int e = 1; e < NEXP; ++e) if (L[e] > L[e1]) e1 = e;
  int e2 = -1;
#pragma unroll
  for (int e = 0; e < NEXP; ++e) {
    if (e == e1) continue;
    if (e2 < 0 || L[e] > L[e2]) e2 = e;
  }
  if (lane == 0) {
    float p2 = expf(L[e2] - L[e1]);   // <= 1
    float w1 = 1.0f / (1.0f + p2);
    float w2 = p2 / (1.0f + p2);
    // padded counters: one 64B cache line per expert -> parallel TCC streams
    int r1 = atomicAdd(&cnt[e1 * CPAD], 1);
    lists[e1 * T_TOK + r1] = t;
    int r2 = atomicAdd(&cnt[e2 * CPAD], 1);
    lists[e2 * T_TOK + r2] = t;
    tokexp[2 * t] = e1;  tokrow[2 * t] = r1;  tokwt[2 * t] = w1;
    tokexp[2 * t + 1] = e2; tokrow[2 * t + 1] = r2; tokwt[2 * t + 1] = w2;
    lists[8 * T_TOK + t] = t;
  }
}

// ---------------- setup ----------------
__global__ void k_setup(const int* __restrict__ cnt, int* __restrict__ off,
                        int* __restrict__ tg, int* __restrict__ tr0,
                        int* __restrict__ tlr, int* __restrict__ ntiles,
                        int* __restrict__ lists) {
  if (threadIdx.x == 0 && blockIdx.x == 0) {
    int o = 0, nt = 0;
    for (int g = 0; g < 9; ++g) {
      int n = (g < 8) ? cnt[g * CPAD] : T_TOK;
      off[g] = o;
      int tm = (n + BM - 1) / BM;
      for (int m = 0; m < tm; ++m) {
        tg[nt] = g; tr0[nt] = o + m * BM; tlr[nt] = m * BM; ++nt;
      }
      for (int r = n; r < tm * BM; ++r) lists[g * T_TOK + r] = 0;
      o += tm * BM;
    }
    off[9] = o;
    ntiles[0] = nt;
  }
}

// ---------------- gate+up GEMM (bf16, all-DMA staging), fused silu ----------------
__global__ __launch_bounds__(256, 3) void k_gateup(
    const unsigned short* __restrict__ xbf, const unsigned short* __restrict__ wg_bf,
    const unsigned short* __restrict__ wu_bf,
    const int* __restrict__ lists, const int* __restrict__ tg,
    const int* __restrict__ tr0, const int* __restrict__ tlr,
    const int* __restrict__ ntiles, unsigned short* __restrict__ acth, int y0) {
  const int nt = ntiles[0];
  const int mt = blockIdx.y + y0;
  if (mt >= nt) return;
  const int grp = tg[mt], row0 = tr0[mt], lrow = tlr[mt];
  const int n0 = blockIdx.x * 64;
  const unsigned short* wgsrc = wg_bf + (long)grp * HDIM * DDIM;
  const unsigned short* wusrc = wu_bf + (long)grp * HDIM * DDIM;

  __shared__ alignas(16) char smem[32768];
  const int AH = 0, BG = 16384, BU = 24576;

  const int tid = threadIdx.x;
  const int lane = tid & 63, wid = tid >> 6;
  const int srow = tid >> 3, gch = tid & 7;

  const unsigned short* asrc[4];
  char* adst[4];
#pragma unroll
  for (int p = 0; p < 4; ++p) {
    int r = p * 32 + srow;
    int tok = lists[grp * T_TOK + lrow + r];
    asrc[p] = xbf + (long)tok * DDIM + ((gch ^ (r & 7)) << 3);
    adst[p] = smem + AH + (p * 32 + wid * 8) * 128;   // wave-uniform base
  }
  const unsigned short* gsrc[2];
  const unsigned short* usrc[2];
  char* bgdst[2];
  char* budst[2];
#pragma unroll
  for (int p = 0; p < 2; ++p) {
    int r = p * 32 + srow;
    gsrc[p] = wgsrc + (long)(n0 + r) * DDIM + ((gch ^ (r & 7)) << 3);
    usrc[p] = wusrc + (long)(n0 + r) * DDIM + ((gch ^ (r & 7)) << 3);
    bgdst[p] = smem + BG + (p * 32 + wid * 8) * 128;
    budst[p] = smem + BU + (p * 32 + wid * 8) * 128;
  }

  f32x4 accg[4][2], accu[4][2];
  f32x4 z4 = {0.f, 0.f, 0.f, 0.f};
#pragma unroll
  for (int m = 0; m < 4; ++m)
#pragma unroll
    for (int n = 0; n < 2; ++n) { accg[m][n] = z4; accu[m][n] = z4; }

  const int wm = wid >> 1, wn = wid & 1;
  int aro[4][2], bro[2][2];
#pragma unroll
  for (int m = 0; m < 4; ++m) {
    int r = wm * 64 + m * 16 + (lane & 15);
#pragma unroll
    for (int kh = 0; kh < 2; ++kh) {
      int c = (kh * 4 + (lane >> 4)) ^ (r & 7);
      aro[m][kh] = r * 128 + c * 16;
    }
  }
#pragma unroll
  for (int n = 0; n < 2; ++n) {
    int r = wn * 32 + n * 16 + (lane & 15);
#pragma unroll
    for (int kh = 0; kh < 2; ++kh) {
      int c = (kh * 4 + (lane >> 4)) ^ (r & 7);
      bro[n][kh] = r * 128 + c * 16;
    }
  }

  for (int k0 = 0; k0 < DDIM; k0 += BK) {
    __syncthreads();
#pragma unroll
    for (int p = 0; p < 4; ++p)
      gload16(asrc[p] + k0, adst[p]);
#pragma unroll
    for (int p = 0; p < 2; ++p) {
      gload16(gsrc[p] + k0, bgdst[p]);
      gload16(usrc[p] + k0, budst[p]);
    }
    __syncthreads();
#pragma unroll
    for (int kh = 0; kh < 2; ++kh) {
      bfrag ah[4];
#pragma unroll
      for (int m = 0; m < 4; ++m)
        ah[m] = *(const bfrag*)(smem + AH + aro[m][kh]);
      bfrag bg[2], bu[2];
#pragma unroll
      for (int n = 0; n < 2; ++n) {
        bg[n] = *(const bfrag*)(smem + BG + bro[n][kh]);
        bu[n] = *(const bfrag*)(smem + BU + bro[n][kh]);
      }
#pragma unroll
      for (int m = 0; m < 4; ++m)
#pragma unroll
        for (int n = 0; n < 2; ++n) {
          accg[m][n] = __builtin_amdgcn_mfma_f32_16x16x32_bf16(ah[m], bg[n], accg[m][n], 0, 0, 0);
          accu[m][n] = __builtin_amdgcn_mfma_f32_16x16x32_bf16(ah[m], bu[n], accu[m][n], 0, 0, 0);
        }
    }
  }
#pragma unroll
  for (int m = 0; m < 4; ++m) {
    int gr0 = row0 + wm * 64 + m * 16 + ((lane >> 4) << 2);
#pragma unroll
    for (int n = 0; n < 2; ++n) {
      int col = n0 + wn * 32 + n * 16 + (lane & 15);
#pragma unroll
      for (int q = 0; q < 4; ++q) {
        float g = accg[m][n][q], u = accu[m][n][q];
        float a = (g / (1.0f + expf(-g))) * u;
        acth[(long)(gr0 + q) * HDIM + col] = f2bf(a);
      }
    }
  }
}

// ---------------- down GEMM (bf16, BM=128 x BN=256, 512 thr, 8 waves) ----------------
__global__ __launch_bounds__(512, 3) void k_down(
    const unsigned short* __restrict__ acth, const unsigned short* __restrict__ wd_bf,
    const int* __restrict__ tg, const int* __restrict__ tr0,
    const int* __restrict__ ntiles, unsigned short* __restrict__ outb) {
  const int nt = ntiles[0];
  // XCD swizzle (kept — helped k_down): nwg = 4*MT_MAX = 832, %8==0
  int flat = blockIdx.y * 4 + blockIdx.x;
  int logical = (flat & 7) * (MT_MAX / 2) + (flat >> 3);   // 104 tiles per XCD
  const int mt = logical >> 2;
  const int n0 = (logical & 3) * 256;
  if (mt >= nt) return;
  const int grp = tg[mt], row0 = tr0[mt];
  const unsigned short* wdsrc = wd_bf + (long)grp * DDIM * HDIM;

  __shared__ alignas(16) char smem[49152];
  const int AH = 0, BH = 16384;

  const int tid = threadIdx.x;
  const int lane = tid & 63, wid = tid >> 6;   // wid 0..7
  const int srow = tid >> 3, gch = tid & 7;    // srow 0..63

  // A tile 128x64 (16KB): 2 passes of 64 rows; B tile 256x64 (32KB): 4 passes
  const unsigned short* asrc[2];
  char* adst[2];
#pragma unroll
  for (int p = 0; p < 2; ++p) {
    int r = p * 64 + srow;
    asrc[p] = acth + (long)(row0 + r) * HDIM + ((gch ^ (r & 7)) << 3);
    adst[p] = smem + AH + (p * 64 + wid * 8) * 128;
  }
  const unsigned short* bsrc[4];
  char* bdst[4];
#pragma unroll
  for (int p = 0; p < 4; ++p) {
    int r = p * 64 + srow;
    bsrc[p] = wdsrc + (long)(n0 + r) * HDIM + ((gch ^ (r & 7)) << 3);
    bdst[p] = smem + BH + (p * 64 + wid * 8) * 128;
  }

  f32x4 acc[4][4];
  f32x4 z4 = {0.f, 0.f, 0.f, 0.f};
#pragma unroll
  for (int m = 0; m < 4; ++m)
#pragma unroll
    for (int n = 0; n < 4; ++n) acc[m][n] = z4;

  const int wm = wid >> 2, wn = wid & 3;   // 2M x 4N waves, 64x64 each
  int aro[4][2], bro[4][2];
#pragma unroll
  for (int m = 0; m < 4; ++m) {
    int r = wm * 64 + m * 16 + (lane & 15);
#pragma unroll
    for (int kh = 0; kh < 2; ++kh) {
      int c = (kh * 4 + (lane >> 4)) ^ (r & 7);
      aro[m][kh] = r * 128 + c * 16;
    }
  }
#pragma unroll
  for (int n = 0; n < 4; ++n) {
    int r = wn * 64 + n * 16 + (lane & 15);
#pragma unroll
    for (int kh = 0; kh < 2; ++kh) {
      int c = (kh * 4 + (lane >> 4)) ^ (r & 7);
      bro[n][kh] = r * 128 + c * 16;
    }
  }

  for (int k0 = 0; k0 < HDIM; k0 += BK) {
    __syncthreads();
#pragma unroll
    for (int p = 0; p < 2; ++p)
      gload16(asrc[p] + k0, adst[p]);
#pragma unroll
    for (int p = 0; p < 4; ++p)
      gload16(bsrc[p] + k0, bdst[p]);
    __syncthreads();
#pragma unroll
    for (int kh = 0; kh < 2; ++kh) {
      bfrag ah[4];
#pragma unroll
      for (int m = 0; m < 4; ++m)
        ah[m] = *(const bfrag*)(smem + AH + aro[m][kh]);
      bfrag bh[4];
#pragma unroll
      for (int n = 0; n < 4; ++n)
        bh[n] = *(const bfrag*)(smem + BH + bro[n][kh]);
#pragma unroll
      for (int m = 0; m < 4; ++m)
#pragma unroll
        for (int n = 0; n < 4; ++n)
          acc[m][n] = __builtin_amdgcn_mfma_f32_16x16x32_bf16(ah[m], bh[n], acc[m][n], 0, 0, 0);
    }
  }
#pragma unroll
  for (int m = 0; m < 4; ++m) {
    int gr0 = row0 + wm * 64 + m * 16 + ((lane >> 4) << 2);
#pragma unroll
    for (int n = 0; n < 4; ++n) {
      int col = n0 + wn * 64 + n * 16 + (lane & 15);
#pragma unroll
      for (int q = 0; q < 4; ++q)
        outb[(long)(gr0 + q) * DDIM + col] = f2bf(acc[m][n][q]);
    }
  }
}

// ---------------- combine ----------------
__global__ __launch_bounds__(256) void k_combine(
    const unsigned short* __restrict__ outb, const int* __restrict__ off,
    const int* __restrict__ tokexp, const int* __restrict__ tokrow,
    const float* __restrict__ tokwt, const float* __restrict__ ls,
    float* __restrict__ out) {
  int t = blockIdx.x;
  int e1 = tokexp[2 * t], e2 = tokexp[2 * t + 1];
  long r1 = off[e1] + tokrow[2 * t];
  long r2 = off[e2] + tokrow[2 * t + 1];
  long rs = off[8] + t;
  float w1 = tokwt[2 * t], w2 = tokwt[2 * t + 1];
  int d = threadIdx.x * 4;
  u16x4 sv = *(const u16x4*)(outb + rs * DDIM + d);
  u16x4 o1 = *(const u16x4*)(outb + r1 * DDIM + d);
  u16x4 o2 = *(const u16x4*)(outb + r2 * DDIM + d);
  f32x4 l4 = *(const f32x4*)(ls + d);
  f32x4 r;
#pragma unroll
  for (int j = 0; j < 4; ++j)
    r[j] = (bf2f(sv[j]) + w1 * bf2f(o1[j]) + w2 * bf2f(o2[j])) * l4[j];
  *(f32x4*)(out + (long)t * DDIM + d) = r;
}

extern "C" void kernel_launch(void* const* d_in, const int* in_sizes, int n_in,
                              void* d_out, int out_size, void* d_ws, size_t ws_size,
                              hipStream_t stream) {
  (void)in_sizes; (void)n_in; (void)out_size;
  const float* x     = (const float*)d_in[0];
  const float* wr    = (const float*)d_in[1];
  const float* sh_wg = (const float*)d_in[2];
  const float* sh_wu = (const float*)d_in[3];
  const float* sh_wd = (const float*)d_in[4];
  const float* ex_wg = (const float*)d_in[5];
  const float* ex_wu = (const float*)d_in[6];
  const float* ex_wd = (const float*)d_in[7];
  const float* ls    = (const float*)d_in[8];

  const long WMAT = (long)HDIM * DDIM;          // 2.097M elems per matrix
  const long W9  = 9L * WMAT;                   // 18.87M elems per weight set

  char* w = (char*)d_ws;
  size_t o = 0;
  auto bump = [&](size_t bytes) {
    void* p = w + o;
    o = (o + bytes + 255) & ~(size_t)255;
    return p;
  };
  // region0: outb (52.4MB) with xbf (16.8MB) aliased at its start.
  unsigned short* outb = (unsigned short*)bump((size_t)RMAX * DDIM * 2);
  unsigned short* xbf  = outb;
  // region1: wg_bf (37.7MB) — k_cvt2(wd) overwrites it AFTER k_gateup.
  unsigned short* wg_bf = (unsigned short*)bump(W9 * 2);
  unsigned short* wd_bf = wg_bf;
  unsigned short* wu_bf = (unsigned short*)bump(W9 * 2);
  unsigned short* acth  = (unsigned short*)bump((size_t)RMAX * HDIM * 2);  // 104.9MB
  int* lists  = (int*)bump(9L * T_TOK * 4);
  int* cnt    = (int*)bump(NEXP * CPAD * 4);   // padded: 64B line per expert
  int* off    = (int*)bump(64);
  int* tg     = (int*)bump(1024);
  int* tr0    = (int*)bump(1024);
  int* tlr    = (int*)bump(1024);
  int* ntiles = (int*)bump(64);
  int* tokexp = (int*)bump((long)T_TOK * 2 * 4);
  int* tokrow = (int*)bump((long)T_TOK * 2 * 4);
  float* tokwt = (float*)bump((long)T_TOK * 2 * 4);

  if (o > ws_size) return;  // diagnostic fail instead of OOB crash

  hipMemsetAsync(cnt, 0, NEXP * CPAD * 4, stream);
  k_router<<<T_TOK / 4, 256, 0, stream>>>(x, wr, xbf, cnt, lists, tokexp, tokrow, tokwt);
  k_setup<<<1, 64, 0, stream>>>(cnt, off, tg, tr0, tlr, ntiles, lists);

  // weight conversion: gate+up in ONE launch before gateup GEMM
  k_cvt4<<<4096, 256, 0, stream>>>(ex_wg, sh_wg, wg_bf, ex_wu, sh_wu, wu_bf,
                                   (8L * WMAT) / 8, WMAT / 8);

  // gateup: unswizzled dispatch order (optimal L3 temporal locality), 2 halves
  dim3 g1(32, MT_MAX / 2);
  k_gateup<<<g1, 256, 0, stream>>>(xbf, wg_bf, wu_bf, lists, tg, tr0, tlr, ntiles,
                                   acth, 0);
  k_gateup<<<g1, 256, 0, stream>>>(xbf, wg_bf, wu_bf, lists, tg, tr0, tlr, ntiles,
                                   acth, MT_MAX / 2);

  // down weights converted after gateup (aliases wg_bf region)
  k_cvt2<<<2048, 256, 0, stream>>>(ex_wd, (8L * WMAT) / 8, sh_wd, WMAT / 8, wd_bf);

  dim3 g2(4, MT_MAX);
  k_down<<<g2, 512, 0, stream>>>(acth, wd_bf, tg, tr0, ntiles, outb);

  k_combine<<<T_TOK, 256, 0, stream>>>(outb, off, tokexp, tokrow, tokwt, ls, (float*)d_out);
}

// Round 12
// 492.639 us; speedup vs baseline: 1.1414x; 1.1414x over previous
//
#include <hip/hip_runtime.h>
#include <hip/hip_bf16.h>

// SharedMoEBlock: B=4,S=2048,D=1024,H=2048,E=8,topk=2
// Round 12: best-of-measured compose. gateup = r9 config (unswizzled 2-way
// split, 2x108us). k_down = r10 config (BN=128/256thr, XCD swizzle, ~123us).
// r11's BN=256/512thr down regressed (occupancy 16.8%, 197us) — reverted.

#define T_TOK 8192
#define DDIM  1024
#define HDIM  2048
#define NEXP  8
#define BM    128
#define BK    64
#define MT_MAX 208
#define RMAX  25600   // max padded rows: routed <=17408 + shared 8192
#define CPAD  16      // cnt stride in ints (64B line per expert)

typedef __attribute__((ext_vector_type(4))) float f32x4;
typedef __attribute__((ext_vector_type(8))) short bfrag;
typedef __attribute__((ext_vector_type(4))) unsigned short u16x4;

static __device__ __forceinline__ unsigned short f2bf(float f) {
  __hip_bfloat16 h = __float2bfloat16(f);
  return __builtin_bit_cast(unsigned short, h);
}
static __device__ __forceinline__ float bf2f(unsigned short u) {
  __hip_bfloat16 h = __builtin_bit_cast(__hip_bfloat16, u);
  return __bfloat162float(h);
}
static __device__ __forceinline__ bfrag cvt8(const float* __restrict__ s) {
  f32x4 v0 = *(const f32x4*)s;
  f32x4 v1 = *(const f32x4*)(s + 4);
  bfrag h;
#pragma unroll
  for (int j = 0; j < 4; ++j) {
    h[j] = (short)f2bf(v0[j]);
    h[4 + j] = (short)f2bf(v1[j]);
  }
  return h;
}
static __device__ __forceinline__ bfrag pack8(f32x4 a, f32x4 b) {
  bfrag h;
#pragma unroll
  for (int j = 0; j < 4; ++j) {
    h[j] = (short)f2bf(a[j]);
    h[4 + j] = (short)f2bf(b[j]);
  }
  return h;
}
static __device__ __forceinline__ void gload16(const void* g, void* l) {
  __builtin_amdgcn_global_load_lds(
      (const __attribute__((address_space(1))) unsigned int*)g,
      (__attribute__((address_space(3))) unsigned int*)l, 16, 0, 0);
}

// ---------------- fp32 -> bf16 convert, 2 sets x 2 sources each ----------------
__global__ __launch_bounds__(256) void k_cvt4(
    const float* __restrict__ ea, const float* __restrict__ sa,
    unsigned short* __restrict__ da,
    const float* __restrict__ eb, const float* __restrict__ sb,
    unsigned short* __restrict__ db, long ne8, long ns8) {
  long tot = ne8 + ns8;
  long i = (long)blockIdx.x * blockDim.x + threadIdx.x;
  long stride = (long)gridDim.x * blockDim.x;
  for (; i < 2 * tot; i += stride) {
    long j = (i < tot) ? i : i - tot;
    const float* e = (i < tot) ? ea : eb;
    const float* sh = (i < tot) ? sa : sb;
    unsigned short* d = (i < tot) ? da : db;
    const float* s = (j < ne8) ? e + j * 8 : sh + (j - ne8) * 8;
    ((bfrag*)d)[j] = cvt8(s);
  }
}

// ---------------- fp32 -> bf16 convert, two sources ----------------
__global__ __launch_bounds__(256) void k_cvt2(const float* __restrict__ a, long na8,
                                              const float* __restrict__ b, long nb8,
                                              unsigned short* __restrict__ dst) {
  long i = (long)blockIdx.x * blockDim.x + threadIdx.x;
  long stride = (long)gridDim.x * blockDim.x;
  long n = na8 + nb8;
  for (; i < n; i += stride) {
    const float* s = (i < na8) ? a + i * 8 : b + (i - na8) * 8;
    ((bfrag*)dst)[i] = cvt8(s);
  }
}

// ---------------- router (+ fused x->bf16 conversion) ----------------
__global__ __launch_bounds__(256) void k_router(const float* __restrict__ x,
                                                const float* __restrict__ wr,
                                                unsigned short* __restrict__ xbf,
                                                int* __restrict__ cnt,
                                                int* __restrict__ lists,
                                                int* __restrict__ tokexp,
                                                int* __restrict__ tokrow,
                                                float* __restrict__ tokwt) {
  int wid = threadIdx.x >> 6, lane = threadIdx.x & 63;
  int t = blockIdx.x * 4 + wid;
  const float* xr = x + (long)t * DDIM;
  f32x4 xf[4];
#pragma unroll
  for (int j = 0; j < 4; ++j) xf[j] = ((const f32x4*)xr)[lane * 4 + j];
  // fused bf16 conversion of x
  bfrag* xrow = (bfrag*)(xbf + (long)t * DDIM);
  xrow[lane * 2] = pack8(xf[0], xf[1]);
  xrow[lane * 2 + 1] = pack8(xf[2], xf[3]);
  float L[NEXP];
#pragma unroll
  for (int e = 0; e < NEXP; ++e) {
    const f32x4* wrow = (const f32x4*)(wr + (long)e * DDIM);
    float p = 0.f;
#pragma unroll
    for (int j = 0; j < 4; ++j) {
      f32x4 w = wrow[lane * 4 + j];
      p += xf[j].x * w.x + xf[j].y * w.y + xf[j].z * w.z + xf[j].w * w.w;
    }
    for (int s = 1; s < 64; s <<= 1) p += __shfl_xor(p, s);
    L[e] = p;
  }
  int e1 = 0;
#pragma unroll
  for (int e = 1; e < NEXP; ++e) if (L[e] > L[e1]) e1 = e;
  int e2 = -1;
#pragma unroll
  for (int e = 0; e < NEXP; ++e) {
    if (e == e1) continue;
    if (e2 < 0 || L[e] > L[e2]) e2 = e;
  }
  if (lane == 0) {
    float p2 = expf(L[e2] - L[e1]);   // <= 1
    float w1 = 1.0f / (1.0f + p2);
    float w2 = p2 / (1.0f + p2);
    // padded counters: one 64B cache line per expert -> parallel TCC streams
    int r1 = atomicAdd(&cnt[e1 * CPAD], 1);
    lists[e1 * T_TOK + r1] = t;
    int r2 = atomicAdd(&cnt[e2 * CPAD], 1);
    lists[e2 * T_TOK + r2] = t;
    tokexp[2 * t] = e1;  tokrow[2 * t] = r1;  tokwt[2 * t] = w1;
    tokexp[2 * t + 1] = e2; tokrow[2 * t + 1] = r2; tokwt[2 * t + 1] = w2;
    lists[8 * T_TOK + t] = t;
  }
}

// ---------------- setup ----------------
__global__ void k_setup(const int* __restrict__ cnt, int* __restrict__ off,
                        int* __restrict__ tg, int* __restrict__ tr0,
                        int* __restrict__ tlr, int* __restrict__ ntiles,
                        int* __restrict__ lists) {
  if (threadIdx.x == 0 && blockIdx.x == 0) {
    int o = 0, nt = 0;
    for (int g = 0; g < 9; ++g) {
      int n = (g < 8) ? cnt[g * CPAD] : T_TOK;
      off[g] = o;
      int tm = (n + BM - 1) / BM;
      for (int m = 0; m < tm; ++m) {
        tg[nt] = g; tr0[nt] = o + m * BM; tlr[nt] = m * BM; ++nt;
      }
      for (int r = n; r < tm * BM; ++r) lists[g * T_TOK + r] = 0;
      o += tm * BM;
    }
    off[9] = o;
    ntiles[0] = nt;
  }
}

// ---------------- gate+up GEMM (bf16, all-DMA staging), fused silu ----------------
__global__ __launch_bounds__(256, 3) void k_gateup(
    const unsigned short* __restrict__ xbf, const unsigned short* __restrict__ wg_bf,
    const unsigned short* __restrict__ wu_bf,
    const int* __restrict__ lists, const int* __restrict__ tg,
    const int* __restrict__ tr0, const int* __restrict__ tlr,
    const int* __restrict__ ntiles, unsigned short* __restrict__ acth, int y0) {
  const int nt = ntiles[0];
  const int mt = blockIdx.y + y0;
  if (mt >= nt) return;
  const int grp = tg[mt], row0 = tr0[mt], lrow = tlr[mt];
  const int n0 = blockIdx.x * 64;
  const unsigned short* wgsrc = wg_bf + (long)grp * HDIM * DDIM;
  const unsigned short* wusrc = wu_bf + (long)grp * HDIM * DDIM;

  __shared__ alignas(16) char smem[32768];
  const int AH = 0, BG = 16384, BU = 24576;

  const int tid = threadIdx.x;
  const int lane = tid & 63, wid = tid >> 6;
  const int srow = tid >> 3, gch = tid & 7;

  const unsigned short* asrc[4];
  char* adst[4];
#pragma unroll
  for (int p = 0; p < 4; ++p) {
    int r = p * 32 + srow;
    int tok = lists[grp * T_TOK + lrow + r];
    asrc[p] = xbf + (long)tok * DDIM + ((gch ^ (r & 7)) << 3);
    adst[p] = smem + AH + (p * 32 + wid * 8) * 128;   // wave-uniform base
  }
  const unsigned short* gsrc[2];
  const unsigned short* usrc[2];
  char* bgdst[2];
  char* budst[2];
#pragma unroll
  for (int p = 0; p < 2; ++p) {
    int r = p * 32 + srow;
    gsrc[p] = wgsrc + (long)(n0 + r) * DDIM + ((gch ^ (r & 7)) << 3);
    usrc[p] = wusrc + (long)(n0 + r) * DDIM + ((gch ^ (r & 7)) << 3);
    bgdst[p] = smem + BG + (p * 32 + wid * 8) * 128;
    budst[p] = smem + BU + (p * 32 + wid * 8) * 128;
  }

  f32x4 accg[4][2], accu[4][2];
  f32x4 z4 = {0.f, 0.f, 0.f, 0.f};
#pragma unroll
  for (int m = 0; m < 4; ++m)
#pragma unroll
    for (int n = 0; n < 2; ++n) { accg[m][n] = z4; accu[m][n] = z4; }

  const int wm = wid >> 1, wn = wid & 1;
  int aro[4][2], bro[2][2];
#pragma unroll
  for (int m = 0; m < 4; ++m) {
    int r = wm * 64 + m * 16 + (lane & 15);
#pragma unroll
    for (int kh = 0; kh < 2; ++kh) {
      int c = (kh * 4 + (lane >> 4)) ^ (r & 7);
      aro[m][kh] = r * 128 + c * 16;
    }
  }
#pragma unroll
  for (int n = 0; n < 2; ++n) {
    int r = wn * 32 + n * 16 + (lane & 15);
#pragma unroll
    for (int kh = 0; kh < 2; ++kh) {
      int c = (kh * 4 + (lane >> 4)) ^ (r & 7);
      bro[n][kh] = r * 128 + c * 16;
    }
  }

  for (int k0 = 0; k0 < DDIM; k0 += BK) {
    __syncthreads();
#pragma unroll
    for (int p = 0; p < 4; ++p)
      gload16(asrc[p] + k0, adst[p]);
#pragma unroll
    for (int p = 0; p < 2; ++p) {
      gload16(gsrc[p] + k0, bgdst[p]);
      gload16(usrc[p] + k0, budst[p]);
    }
    __syncthreads();
#pragma unroll
    for (int kh = 0; kh < 2; ++kh) {
      bfrag ah[4];
#pragma unroll
      for (int m = 0; m < 4; ++m)
        ah[m] = *(const bfrag*)(smem + AH + aro[m][kh]);
      bfrag bg[2], bu[2];
#pragma unroll
      for (int n = 0; n < 2; ++n) {
        bg[n] = *(const bfrag*)(smem + BG + bro[n][kh]);
        bu[n] = *(const bfrag*)(smem + BU + bro[n][kh]);
      }
#pragma unroll
      for (int m = 0; m < 4; ++m)
#pragma unroll
        for (int n = 0; n < 2; ++n) {
          accg[m][n] = __builtin_amdgcn_mfma_f32_16x16x32_bf16(ah[m], bg[n], accg[m][n], 0, 0, 0);
          accu[m][n] = __builtin_amdgcn_mfma_f32_16x16x32_bf16(ah[m], bu[n], accu[m][n], 0, 0, 0);
        }
    }
  }
#pragma unroll
  for (int m = 0; m < 4; ++m) {
    int gr0 = row0 + wm * 64 + m * 16 + ((lane >> 4) << 2);
#pragma unroll
    for (int n = 0; n < 2; ++n) {
      int col = n0 + wn * 32 + n * 16 + (lane & 15);
#pragma unroll
      for (int q = 0; q < 4; ++q) {
        float g = accg[m][n][q], u = accu[m][n][q];
        float a = (g / (1.0f + expf(-g))) * u;
        acth[(long)(gr0 + q) * HDIM + col] = f2bf(a);
      }
    }
  }
}

// ---------------- down GEMM (bf16, BN=128, 256thr, XCD swizzle) ----------------
__global__ __launch_bounds__(256, 3) void k_down(
    const unsigned short* __restrict__ acth, const unsigned short* __restrict__ wd_bf,
    const int* __restrict__ tg, const int* __restrict__ tr0,
    const int* __restrict__ ntiles, unsigned short* __restrict__ outb) {
  const int nt = ntiles[0];
  int flat = blockIdx.y * 8 + blockIdx.x;             // nwg = 8*MT_MAX, %8==0
  int logical = (flat & 7) * MT_MAX + (flat >> 3);
  const int mt = logical >> 3;
  const int n0 = (logical & 7) * 128;
  if (mt >= nt) return;
  const int grp = tg[mt], row0 = tr0[mt];
  const unsigned short* wdsrc = wd_bf + (long)grp * DDIM * HDIM;

  __shared__ alignas(16) char smem[32768];
  const int AH = 0, BH = 16384;

  const int tid = threadIdx.x;
  const int lane = tid & 63, wid = tid >> 6;
  const int srow = tid >> 3, gch = tid & 7;

  const unsigned short* asrc[4];
  char* adst[4];
#pragma unroll
  for (int p = 0; p < 4; ++p) {
    int r = p * 32 + srow;
    asrc[p] = acth + (long)(row0 + r) * HDIM + ((gch ^ (r & 7)) << 3);
    adst[p] = smem + AH + (p * 32 + wid * 8) * 128;
  }
  const unsigned short* bsrc[4];
  char* bdst[4];
#pragma unroll
  for (int p = 0; p < 4; ++p) {
    int r = p * 32 + srow;
    bsrc[p] = wdsrc + (long)(n0 + r) * HDIM + ((gch ^ (r & 7)) << 3);
    bdst[p] = smem + BH + (p * 32 + wid * 8) * 128;
  }

  f32x4 acc[4][4];
  f32x4 z4 = {0.f, 0.f, 0.f, 0.f};
#pragma unroll
  for (int m = 0; m < 4; ++m)
#pragma unroll
    for (int n = 0; n < 4; ++n) acc[m][n] = z4;

  const int wm = wid >> 1, wn = wid & 1;     // wave: 64 rows x 64 cols
  int aro[4][2], bro[4][2];
#pragma unroll
  for (int m = 0; m < 4; ++m) {
    int r = wm * 64 + m * 16 + (lane & 15);
#pragma unroll
    for (int kh = 0; kh < 2; ++kh) {
      int c = (kh * 4 + (lane >> 4)) ^ (r & 7);
      aro[m][kh] = r * 128 + c * 16;
    }
  }
#pragma unroll
  for (int n = 0; n < 4; ++n) {
    int r = wn * 64 + n * 16 + (lane & 15);
#pragma unroll
    for (int kh = 0; kh < 2; ++kh) {
      int c = (kh * 4 + (lane >> 4)) ^ (r & 7);
      bro[n][kh] = r * 128 + c * 16;
    }
  }

  for (int k0 = 0; k0 < HDIM; k0 += BK) {
    __syncthreads();
#pragma unroll
    for (int p = 0; p < 4; ++p)
      gload16(asrc[p] + k0, adst[p]);
#pragma unroll
    for (int p = 0; p < 4; ++p)
      gload16(bsrc[p] + k0, bdst[p]);
    __syncthreads();
#pragma unroll
    for (int kh = 0; kh < 2; ++kh) {
      bfrag ah[4];
#pragma unroll
      for (int m = 0; m < 4; ++m)
        ah[m] = *(const bfrag*)(smem + AH + aro[m][kh]);
      bfrag bh[4];
#pragma unroll
      for (int n = 0; n < 4; ++n)
        bh[n] = *(const bfrag*)(smem + BH + bro[n][kh]);
#pragma unroll
      for (int m = 0; m < 4; ++m)
#pragma unroll
        for (int n = 0; n < 4; ++n)
          acc[m][n] = __builtin_amdgcn_mfma_f32_16x16x32_bf16(ah[m], bh[n], acc[m][n], 0, 0, 0);
    }
  }
#pragma unroll
  for (int m = 0; m < 4; ++m) {
    int gr0 = row0 + wm * 64 + m * 16 + ((lane >> 4) << 2);
#pragma unroll
    for (int n = 0; n < 4; ++n) {
      int col = n0 + wn * 64 + n * 16 + (lane & 15);
#pragma unroll
      for (int q = 0; q < 4; ++q)
        outb[(long)(gr0 + q) * DDIM + col] = f2bf(acc[m][n][q]);
    }
  }
}

// ---------------- combine ----------------
__global__ __launch_bounds__(256) void k_combine(
    const unsigned short* __restrict__ outb, const int* __restrict__ off,
    const int* __restrict__ tokexp, const int* __restrict__ tokrow,
    const float* __restrict__ tokwt, const float* __restrict__ ls,
    float* __restrict__ out) {
  int t = blockIdx.x;
  int e1 = tokexp[2 * t], e2 = tokexp[2 * t + 1];
  long r1 = off[e1] + tokrow[2 * t];
  long r2 = off[e2] + tokrow[2 * t + 1];
  long rs = off[8] + t;
  float w1 = tokwt[2 * t], w2 = tokwt[2 * t + 1];
  int d = threadIdx.x * 4;
  u16x4 sv = *(const u16x4*)(outb + rs * DDIM + d);
  u16x4 o1 = *(const u16x4*)(outb + r1 * DDIM + d);
  u16x4 o2 = *(const u16x4*)(outb + r2 * DDIM + d);
  f32x4 l4 = *(const f32x4*)(ls + d);
  f32x4 r;
#pragma unroll
  for (int j = 0; j < 4; ++j)
    r[j] = (bf2f(sv[j]) + w1 * bf2f(o1[j]) + w2 * bf2f(o2[j])) * l4[j];
  *(f32x4*)(out + (long)t * DDIM + d) = r;
}

extern "C" void kernel_launch(void* const* d_in, const int* in_sizes, int n_in,
                              void* d_out, int out_size, void* d_ws, size_t ws_size,
                              hipStream_t stream) {
  (void)in_sizes; (void)n_in; (void)out_size;
  const float* x     = (const float*)d_in[0];
  const float* wr    = (const float*)d_in[1];
  const float* sh_wg = (const float*)d_in[2];
  const float* sh_wu = (const float*)d_in[3];
  const float* sh_wd = (const float*)d_in[4];
  const float* ex_wg = (const float*)d_in[5];
  const float* ex_wu = (const float*)d_in[6];
  const float* ex_wd = (const float*)d_in[7];
  const float* ls    = (const float*)d_in[8];

  const long WMAT = (long)HDIM * DDIM;          // 2.097M elems per matrix
  const long W9  = 9L * WMAT;                   // 18.87M elems per weight set

  char* w = (char*)d_ws;
  size_t o = 0;
  auto bump = [&](size_t bytes) {
    void* p = w + o;
    o = (o + bytes + 255) & ~(size_t)255;
    return p;
  };
  // region0: outb (52.4MB) with xbf (16.8MB) aliased at its start.
  unsigned short* outb = (unsigned short*)bump((size_t)RMAX * DDIM * 2);
  unsigned short* xbf  = outb;
  // region1: wg_bf (37.7MB) — k_cvt2(wd) overwrites it AFTER k_gateup.
  unsigned short* wg_bf = (unsigned short*)bump(W9 * 2);
  unsigned short* wd_bf = wg_bf;
  unsigned short* wu_bf = (unsigned short*)bump(W9 * 2);
  unsigned short* acth  = (unsigned short*)bump((size_t)RMAX * HDIM * 2);  // 104.9MB
  int* lists  = (int*)bump(9L * T_TOK * 4);
  int* cnt    = (int*)bump(NEXP * CPAD * 4);   // padded: 64B line per expert
  int* off    = (int*)bump(64);
  int* tg     = (int*)bump(1024);
  int* tr0    = (int*)bump(1024);
  int* tlr    = (int*)bump(1024);
  int* ntiles = (int*)bump(64);
  int* tokexp = (int*)bump((long)T_TOK * 2 * 4);
  int* tokrow = (int*)bump((long)T_TOK * 2 * 4);
  float* tokwt = (float*)bump((long)T_TOK * 2 * 4);

  if (o > ws_size) return;  // diagnostic fail instead of OOB crash

  hipMemsetAsync(cnt, 0, NEXP * CPAD * 4, stream);
  k_router<<<T_TOK / 4, 256, 0, stream>>>(x, wr, xbf, cnt, lists, tokexp, tokrow, tokwt);
  k_setup<<<1, 64, 0, stream>>>(cnt, off, tg, tr0, tlr, ntiles, lists);

  // weight conversion: gate+up in ONE launch before gateup GEMM
  k_cvt4<<<4096, 256, 0, stream>>>(ex_wg, sh_wg, wg_bf, ex_wu, sh_wu, wu_bf,
                                   (8L * WMAT) / 8, WMAT / 8);

  // gateup: unswizzled dispatch order (optimal L3 temporal locality), 2 halves
  dim3 g1(32, MT_MAX / 2);
  k_gateup<<<g1, 256, 0, stream>>>(xbf, wg_bf, wu_bf, lists, tg, tr0, tlr, ntiles,
                                   acth, 0);
  k_gateup<<<g1, 256, 0, stream>>>(xbf, wg_bf, wu_bf, lists, tg, tr0, tlr, ntiles,
                                   acth, MT_MAX / 2);

  // down weights converted after gateup (aliases wg_bf region)
  k_cvt2<<<2048, 256, 0, stream>>>(ex_wd, (8L * WMAT) / 8, sh_wd, WMAT / 8, wd_bf);

  dim3 g2(8, MT_MAX);
  k_down<<<g2, 256, 0, stream>>>(acth, wd_bf, tg, tr0, ntiles, outb);

  k_combine<<<T_TOK, 256, 0, stream>>>(outb, off, tokexp, tokrow, tokwt, ls, (float*)d_out);
}